// Round 8
// baseline (2943.475 us; speedup 1.0000x reference)
//
#include <hip/hip_runtime.h>

#define T_ 2048
#define B_ 128
#define IN_ 64
#define H_ 128
#define OUT_ 32
#define CH_ 32          // steps per ring chunk (sync amortization)
#define RING_ 2         // chunks in flight (RING_*CH_ = 64 -> slot = t & 63)

typedef _Float16 half8 __attribute__((ext_vector_type(8)));
typedef _Float16 half4v __attribute__((ext_vector_type(4)));
typedef float float4v __attribute__((ext_vector_type(4)));

#define XSTR 144        // bytes per batch-row, x staging
#define HSTR 272        // bytes per batch-row, h staging
#define GRP_ELEMS ((size_t)RING_ * CH_ * 16 * 128)
#define RING_BYTES ((size_t)8 * GRP_ELEMS * 2)

#define NLOG2E  (-1.4426950408889634f)   // i,f,o rows pre-scaled by -log2(e)
#define C2LOG2E ( 2.8853900817779268f)   // g rows pre-scaled by 2*log2(e)

// exp2 via builtin: backend inserts the TRANS-use wait state (R1 lesson:
// raw inline-asm v_exp_f32 lacks the hazard s_nop -> sporadic corruption).
__device__ __forceinline__ float exp2_hw(float x) {
#if __has_builtin(__builtin_amdgcn_exp2f)
  return __builtin_amdgcn_exp2f(x);
#else
  return exp2f(x);
#endif
}
__device__ __forceinline__ float sigm_pre(float xs) {   // xs = -log2e * x
  return __builtin_amdgcn_rcpf(1.0f + exp2_hw(xs));
}
__device__ __forceinline__ float tanh_pre(float xs) {   // xs = 2*log2e * x
  return fmaf(-2.0f, __builtin_amdgcn_rcpf(1.0f + exp2_hw(xs)), 1.0f);
}
__device__ __forceinline__ float tanh_c(float x) { return tanh_pre(x * C2LOG2E); }

__device__ __forceinline__ float4v sigm4(float4v a) {
  float4v r;
#pragma unroll
  for (int i = 0; i < 4; ++i) r[i] = sigm_pre(a[i]);
  return r;
}
__device__ __forceinline__ float4v tanh4(float4v a) {
  float4v r;
#pragma unroll
  for (int i = 0; i < 4; ++i) r[i] = tanh_pre(a[i]);
  return r;
}

// Light barrier: LDS-visibility only (no vmcnt drain -> ring stores /
// prefetch loads stay in flight across steps). Rule #18: sched_barrier
// fences around the asm so nothing is hoisted past the waitcnt.
__device__ __forceinline__ void bar_light() {
  __builtin_amdgcn_sched_barrier(0);
  asm volatile("s_waitcnt lgkmcnt(0)" ::: "memory");
  __builtin_amdgcn_s_barrier();
  asm volatile("" ::: "memory");
  __builtin_amdgcn_sched_barrier(0);
}
// Full barrier: also drains vmcnt in EVERY wave (required before the
// producer's flag release: all waves' ring stores must be complete).
__device__ __forceinline__ void bar_full() {
  __builtin_amdgcn_sched_barrier(0);
  asm volatile("s_waitcnt vmcnt(0) lgkmcnt(0)" ::: "memory");
  __builtin_amdgcn_s_barrier();
  asm volatile("" ::: "memory");
  __builtin_amdgcn_sched_barrier(0);
}

__device__ __forceinline__ half8 make_afrag(const float* __restrict__ W, int K, int row, int col, float sc) {
  const float* p = W + (size_t)row * K + col;
  float4 a = *(const float4*)p;
  float4 b = *(const float4*)(p + 4);
  half8 h;
  h[0]=(_Float16)(a.x*sc); h[1]=(_Float16)(a.y*sc); h[2]=(_Float16)(a.z*sc); h[3]=(_Float16)(a.w*sc);
  h[4]=(_Float16)(b.x*sc); h[5]=(_Float16)(b.y*sc); h[6]=(_Float16)(b.z*sc); h[7]=(_Float16)(b.w*sc);
  return h;
}

__device__ __forceinline__ void wait_ge(int* p, int want) {
  while (__hip_atomic_load(p, __ATOMIC_RELAXED, __HIP_MEMORY_SCOPE_AGENT) < want)
    __builtin_amdgcn_s_sleep(2);
}

__global__ void ring_init(int* f) { if (threadIdx.x < 16) f[threadIdx.x] = 0; }

__global__ __launch_bounds__(512) void lstm_wavefront(
    const float* __restrict__ x, const float* __restrict__ w_ih0,
    const float* __restrict__ w_hh0, const float* __restrict__ w_ih1,
    const float* __restrict__ w_hh1, const float* __restrict__ fc_w,
    const float* __restrict__ fc_b, float* __restrict__ out, char* __restrict__ ws)
{
  const int tid  = threadIdx.x, lane = tid & 63, w = tid >> 6;
  const int quad = lane >> 4, n = lane & 15;
  const int g = blockIdx.x & 7, layer = blockIdx.x >> 3;  // L0/L1 pair per XCD
  _Float16* ring = (_Float16*)ws + (size_t)g * GRP_ELEMS;
  int* flag     = (int*)(ws + RING_BYTES) + g;        // chunks produced by L0
  int* consumed = (int*)(ws + RING_BYTES) + 8 + g;    // chunks consumed by L1

  __shared__ char sh_x[4 * 16 * XSTR];   // 4-deep: x staged 2 steps ahead
  __shared__ char sh_h[2 * 16 * HSTR];   // double-buffered h

  const size_t hn_base = (size_t)T_ * B_ * OUT_;
  float4v c = {0.f, 0.f, 0.f, 0.f};
  float hf[4] = {0.f, 0.f, 0.f, 0.f};

  for (int i = tid; i < 2 * 16 * HSTR / 4; i += 512) ((unsigned*)sh_h)[i] = 0u;

  if (layer == 0) {
    // ================= LAYER 0 (producer) =================
    half8 a_x[4][2], a_h[4][4];
#pragma unroll
    for (int gt = 0; gt < 4; ++gt) {
      const float sc = (gt == 2) ? C2LOG2E : NLOG2E;
      const int row = gt * H_ + w * 16 + n;
#pragma unroll
      for (int kt = 0; kt < 2; ++kt) a_x[gt][kt] = make_afrag(w_ih0, IN_, row, kt * 32 + quad * 8, sc);
#pragma unroll
      for (int kt = 0; kt < 4; ++kt) a_h[gt][kt] = make_afrag(w_hh0, H_, row, kt * 32 + quad * 8, sc);
    }
    const int xn = tid >> 5, xk = (tid & 31) * 2;
#pragma unroll
    for (int k = 0; k < 2; ++k) {   // stage x(0), x(1)
      float2 xv = *(const float2*)(x + ((size_t)k * B_ + g * 16 + xn) * IN_ + xk);
      _Float16* d = (_Float16*)(sh_x + k * 16 * XSTR + xn * XSTR + xk * 2);
      d[0] = (_Float16)xv.x; d[1] = (_Float16)xv.y;
    }
    __syncthreads();
    // xacc(0): x-projection of step 0 (off the post-barrier critical path)
    float4v xacc[4];
    {
      half8 Bx[2];
#pragma unroll
      for (int kt = 0; kt < 2; ++kt)
        Bx[kt] = *(const half8*)(sh_x + n * XSTR + (kt * 32 + quad * 8) * 2);
#pragma unroll
      for (int gt = 0; gt < 4; ++gt) xacc[gt] = (float4v){0.f, 0.f, 0.f, 0.f};
#pragma unroll
      for (int kt = 0; kt < 2; ++kt)
#pragma unroll
        for (int gt = 0; gt < 4; ++gt)
          xacc[gt] = __builtin_amdgcn_mfma_f32_16x16x32_f16(a_x[gt][kt], Bx[kt], xacc[gt], 0, 0, 0);
    }
    half4v hh_def = {0, 0, 0, 0};

    for (int t = 0; t < T_; ++t) {
      const int ck = t >> 5, s = t & (CH_ - 1);
      if (s == 0 && ck >= RING_) wait_ge(consumed, ck - 1);  // all threads poll
      // deferred ring store of y0(t-1): stays in flight (no per-step drain)
      if (t > 0)
        *(half4v*)(ring + ((size_t)((t - 1) & 63) * 16 + n) * 128 + w * 16 + quad * 4) = hh_def;
      float2 xv = make_float2(0.f, 0.f);
      if (t + 2 < T_) xv = *(const float2*)(x + ((size_t)(t + 2) * B_ + g * 16 + xn) * IN_ + xk);

      // post-barrier critical path: ds_read Bh -> 4-link h-MFMA chain -> acts
      // (x-part already in xacc, computed in previous step's tail)
      half8 Bh[4];
#pragma unroll
      for (int kt = 0; kt < 4; ++kt)
        Bh[kt] = *(const half8*)(sh_h + (t & 1) * 16 * HSTR + n * HSTR + (kt * 32 + quad * 8) * 2);
      float4v acc[4];
#pragma unroll
      for (int gt = 0; gt < 4; ++gt)
        acc[gt] = __builtin_amdgcn_mfma_f32_16x16x32_f16(a_h[gt][0], Bh[0], xacc[gt], 0, 0, 0);
#pragma unroll
      for (int kt = 1; kt < 4; ++kt)
#pragma unroll
        for (int gt = 0; gt < 4; ++gt)
          acc[gt] = __builtin_amdgcn_mfma_f32_16x16x32_f16(a_h[gt][kt], Bh[kt], acc[gt], 0, 0, 0);
      float4v ga[4];
#pragma unroll
      for (int gt = 0; gt < 4; ++gt) ga[gt] = (gt == 2) ? tanh4(acc[gt]) : sigm4(acc[gt]);

      half4v hh;
#pragma unroll
      for (int r = 0; r < 4; ++r) {
        c[r] = fmaf(ga[1][r], c[r], ga[0][r] * ga[2][r]);
        hf[r] = ga[3][r] * tanh_c(c[r]);
        hh[r] = (_Float16)hf[r];
      }
      *(half4v*)(sh_h + ((t & 1) ^ 1) * 16 * HSTR + n * HSTR + (w * 16 + quad * 4) * 2) = hh;
      hh_def = hh;
      if (t + 2 < T_) {
        _Float16* d = (_Float16*)(sh_x + ((t + 2) & 3) * 16 * XSTR + xn * XSTR + xk * 2);
        d[0] = (_Float16)xv.x; d[1] = (_Float16)xv.y;
      }
      // tail precompute of x-part for t+1 (sh_x slot (t+1)&3 written at
      // t-1, stable; register-only output carried across the barrier)
      if (t + 1 < T_) {
        half8 Bxn[2];
#pragma unroll
        for (int kt = 0; kt < 2; ++kt)
          Bxn[kt] = *(const half8*)(sh_x + ((t + 1) & 3) * 16 * XSTR + n * XSTR + (kt * 32 + quad * 8) * 2);
#pragma unroll
        for (int gt = 0; gt < 4; ++gt) xacc[gt] = (float4v){0.f, 0.f, 0.f, 0.f};
#pragma unroll
        for (int kt = 0; kt < 2; ++kt)
#pragma unroll
          for (int gt = 0; gt < 4; ++gt)
            xacc[gt] = __builtin_amdgcn_mfma_f32_16x16x32_f16(a_x[gt][kt], Bxn[kt], xacc[gt], 0, 0, 0);
      }
      // full drain only at chunk boundary (flag release needs ALL waves'
      // ring stores complete); light barrier otherwise
      if (s == 0) bar_full(); else bar_light();
      if (tid == 0 && s == 0 && t > 0) {     // chunks 0..ck-1 fully stored+drained
        __builtin_amdgcn_fence(__ATOMIC_RELEASE, "agent");
        __hip_atomic_store(flag, ck, __ATOMIC_RELAXED, __HIP_MEMORY_SCOPE_AGENT);
      }
    }
    // epilogue: final y0(T-1) + flag T_/CH_
    *(half4v*)(ring + ((size_t)((T_ - 1) & 63) * 16 + n) * 128 + w * 16 + quad * 4) = hh_def;
    bar_full();
    if (tid == 0) {
      __builtin_amdgcn_fence(__ATOMIC_RELEASE, "agent");
      __hip_atomic_store(flag, T_ / CH_, __ATOMIC_RELAXED, __HIP_MEMORY_SCOPE_AGENT);
    }
    {
      float* hn = out + hn_base;
      float* cn = out + hn_base + 2 * (size_t)B_ * H_;
      size_t idx = (size_t)(g * 16 + n) * H_ + w * 16 + quad * 4;
      *(float4*)(hn + idx) = make_float4(hf[0], hf[1], hf[2], hf[3]);
      *(float4*)(cn + idx) = make_float4(c[0], c[1], c[2], c[3]);
    }
  } else {
    // ================= LAYER 1 + FC (consumer) =================
    half8 a_i[4][4], a_h[4][4], a_fc[4];
#pragma unroll
    for (int gt = 0; gt < 4; ++gt) {
      const float sc = (gt == 2) ? C2LOG2E : NLOG2E;
      const int row = gt * H_ + w * 16 + n;
#pragma unroll
      for (int kt = 0; kt < 4; ++kt) {
        a_i[gt][kt] = make_afrag(w_ih1, H_, row, kt * 32 + quad * 8, sc);
        a_h[gt][kt] = make_afrag(w_hh1, H_, row, kt * 32 + quad * 8, sc);
      }
    }
    float4 fb = make_float4(0.f, 0.f, 0.f, 0.f);
    if (w < 2) {
#pragma unroll
      for (int kt = 0; kt < 4; ++kt) a_fc[kt] = make_afrag(fc_w, H_, w * 16 + n, kt * 32 + quad * 8, 1.0f);
      fb = *(const float4*)(fc_b + w * 16 + quad * 4);
    }
    __syncthreads();
    half8 Byc[4];       // prefetch buffer; consumed by the tail precompute
    float4v yacc[4];    // By-projection of the CURRENT step, carried

    for (int t = 0; t < T_; ++t) {
      const int ck = t >> 5, s = t & (CH_ - 1);
      if (s == 0) {                          // chunk boundary: serial path
        wait_ge(flag, ck + 1);
        __builtin_amdgcn_fence(__ATOMIC_ACQUIRE, "agent");
        const _Float16* yp = ring + ((size_t)(t & 63) * 16 + n) * 128 + quad * 8;
#pragma unroll
        for (int kt = 0; kt < 4; ++kt) Byc[kt] = *(const half8*)(yp + kt * 32);
#pragma unroll
        for (int gt = 0; gt < 4; ++gt) yacc[gt] = (float4v){0.f, 0.f, 0.f, 0.f};
#pragma unroll
        for (int kt = 0; kt < 4; ++kt)
#pragma unroll
          for (int gt = 0; gt < 4; ++gt)
            yacc[gt] = __builtin_amdgcn_mfma_f32_16x16x32_f16(a_i[gt][kt], Byc[kt], yacc[gt], 0, 0, 0);
      }
      // h1(t-1) fragments from LDS; FC(t-1) reuses them
      half8 Bh[4];
#pragma unroll
      for (int kt = 0; kt < 4; ++kt)
        Bh[kt] = *(const half8*)(sh_h + (t & 1) * 16 * HSTR + n * HSTR + (kt * 32 + quad * 8) * 2);
      // issue By(t+1) prefetch early: consumed at this step's TAIL (~500cy
      // slack to L2); Byc is dead by here (folded into yacc)
      const bool pf = (s != CH_ - 1) && (t + 1 < T_);
      if (pf) {
        const _Float16* yp = ring + ((size_t)((t + 1) & 63) * 16 + n) * 128 + quad * 8;
#pragma unroll
        for (int kt = 0; kt < 4; ++kt) Byc[kt] = *(const half8*)(yp + kt * 32);
      }
      if (w < 2 && t > 0) {
        // FC as two 2-deep chains
        float4v af0 = {0.f, 0.f, 0.f, 0.f}, af1 = {0.f, 0.f, 0.f, 0.f};
        af0 = __builtin_amdgcn_mfma_f32_16x16x32_f16(a_fc[0], Bh[0], af0, 0, 0, 0);
        af1 = __builtin_amdgcn_mfma_f32_16x16x32_f16(a_fc[1], Bh[1], af1, 0, 0, 0);
        af0 = __builtin_amdgcn_mfma_f32_16x16x32_f16(a_fc[2], Bh[2], af0, 0, 0, 0);
        af1 = __builtin_amdgcn_mfma_f32_16x16x32_f16(a_fc[3], Bh[3], af1, 0, 0, 0);
        float* op = out + ((size_t)(t - 1) * B_ + g * 16 + n) * OUT_ + w * 16 + quad * 4;
        *(float4*)op = make_float4(af0[0] + af1[0] + fb.x, af0[1] + af1[1] + fb.y,
                                   af0[2] + af1[2] + fb.z, af0[3] + af1[3] + fb.w);
      }
      // post-barrier critical path: only the h-part (By-part is in yacc)
      float4v acc[4];
#pragma unroll
      for (int gt = 0; gt < 4; ++gt)
        acc[gt] = __builtin_amdgcn_mfma_f32_16x16x32_f16(a_h[gt][0], Bh[0], yacc[gt], 0, 0, 0);
#pragma unroll
      for (int kt = 1; kt < 4; ++kt)
#pragma unroll
        for (int gt = 0; gt < 4; ++gt)
          acc[gt] = __builtin_amdgcn_mfma_f32_16x16x32_f16(a_h[gt][kt], Bh[kt], acc[gt], 0, 0, 0);
      float4v ga[4];
#pragma unroll
      for (int gt = 0; gt < 4; ++gt) ga[gt] = (gt == 2) ? tanh4(acc[gt]) : sigm4(acc[gt]);

      half4v hh;
#pragma unroll
      for (int r = 0; r < 4; ++r) {
        c[r] = fmaf(ga[1][r], c[r], ga[0][r] * ga[2][r]);
        hf[r] = ga[3][r] * tanh_c(c[r]);
        hh[r] = (_Float16)hf[r];
      }
      *(half4v*)(sh_h + ((t & 1) ^ 1) * 16 * HSTR + n * HSTR + (w * 16 + quad * 4) * 2) = hh;
      // tail precompute of By-part for t+1 (register-only; Byc prefetched
      // ~500cy ago; carried across the barrier in yacc)
      if (pf) {
#pragma unroll
        for (int gt = 0; gt < 4; ++gt) yacc[gt] = (float4v){0.f, 0.f, 0.f, 0.f};
#pragma unroll
        for (int kt = 0; kt < 4; ++kt)
#pragma unroll
          for (int gt = 0; gt < 4; ++gt)
            yacc[gt] = __builtin_amdgcn_mfma_f32_16x16x32_f16(a_i[gt][kt], Byc[kt], yacc[gt], 0, 0, 0);
      }
      bar_light();   // consumed-release needs only register-consumed reads
      if (s == CH_ - 1 && tid == 0) {
        __builtin_amdgcn_fence(__ATOMIC_RELEASE, "agent");
        __hip_atomic_store(consumed, ck + 1, __ATOMIC_RELAXED, __HIP_MEMORY_SCOPE_AGENT);
      }
    }
    // FC(T-1) from sh_h slot (T_&1)=0 = h1(T-1)
    if (w < 2) {
      float4v af = {0.f, 0.f, 0.f, 0.f};
#pragma unroll
      for (int kt = 0; kt < 4; ++kt) {
        half8 Bh = *(const half8*)(sh_h + (T_ & 1) * 16 * HSTR + n * HSTR + (kt * 32 + quad * 8) * 2);
        af = __builtin_amdgcn_mfma_f32_16x16x32_f16(a_fc[kt], Bh, af, 0, 0, 0);
      }
      float* op = out + ((size_t)(T_ - 1) * B_ + g * 16 + n) * OUT_ + w * 16 + quad * 4;
      *(float4*)op = make_float4(af[0] + fb.x, af[1] + fb.y, af[2] + fb.z, af[3] + fb.w);
    }
    {
      float* hn = out + hn_base + (size_t)B_ * H_;
      float* cn = out + hn_base + 3 * (size_t)B_ * H_;
      size_t idx = (size_t)(g * 16 + n) * H_ + w * 16 + quad * 4;
      *(float4*)(hn + idx) = make_float4(hf[0], hf[1], hf[2], hf[3]);
      *(float4*)(cn + idx) = make_float4(c[0], c[1], c[2], c[3]);
    }
  }
}

extern "C" void kernel_launch(void* const* d_in, const int* in_sizes, int n_in,
                              void* d_out, int out_size, void* d_ws, size_t ws_size,
                              hipStream_t stream) {
  const float* x     = (const float*)d_in[0];
  const float* w_ih0 = (const float*)d_in[1];
  const float* w_hh0 = (const float*)d_in[2];
  const float* w_ih1 = (const float*)d_in[3];
  const float* w_hh1 = (const float*)d_in[4];
  const float* fc_w  = (const float*)d_in[5];
  const float* fc_b  = (const float*)d_in[6];
  char* ws = (char*)d_ws;
  ring_init<<<1, 64, 0, stream>>>((int*)(ws + RING_BYTES));
  lstm_wavefront<<<16, 512, 0, stream>>>(x, w_ih0, w_hh0, w_ih1, w_hh1,
                                         fc_w, fc_b, (float*)d_out, ws);
}

// Round 9
// 2894.834 us; speedup vs baseline: 1.0168x; 1.0168x over previous
//
#include <hip/hip_runtime.h>

#define T_ 2048
#define B_ 128
#define IN_ 64
#define H_ 128
#define OUT_ 32
#define CH_ 32          // steps per ring chunk (sync amortization)
#define RING_ 2         // chunks in flight (RING_*CH_ = 64 -> slot = t & 63)

typedef _Float16 half8 __attribute__((ext_vector_type(8)));
typedef _Float16 half4v __attribute__((ext_vector_type(4)));
typedef float float4v __attribute__((ext_vector_type(4)));

#define XSTR 144        // bytes per batch-row, x staging
#define HSTR 272        // bytes per batch-row, h staging
#define GRP_ELEMS ((size_t)RING_ * CH_ * 16 * 128)
#define RING_BYTES ((size_t)8 * GRP_ELEMS * 2)

#define NLOG2E  (-1.4426950408889634f)   // i,f,o rows pre-scaled by -log2(e)
#define C2LOG2E ( 2.8853900817779268f)   // g rows pre-scaled by 2*log2(e)

// exp2 via builtin: backend inserts the TRANS-use wait state (R1 lesson:
// raw inline-asm v_exp_f32 lacks the hazard s_nop -> sporadic corruption).
__device__ __forceinline__ float exp2_hw(float x) {
#if __has_builtin(__builtin_amdgcn_exp2f)
  return __builtin_amdgcn_exp2f(x);
#else
  return exp2f(x);
#endif
}
__device__ __forceinline__ float sigm_pre(float xs) {   // xs = -log2e * x
  return __builtin_amdgcn_rcpf(1.0f + exp2_hw(xs));
}
__device__ __forceinline__ float tanh_pre(float xs) {   // xs = 2*log2e * x
  return fmaf(-2.0f, __builtin_amdgcn_rcpf(1.0f + exp2_hw(xs)), 1.0f);
}
__device__ __forceinline__ float tanh_c(float x) { return tanh_pre(x * C2LOG2E); }

__device__ __forceinline__ float4v sigm4(float4v a) {
  float4v r;
#pragma unroll
  for (int i = 0; i < 4; ++i) r[i] = sigm_pre(a[i]);
  return r;
}
__device__ __forceinline__ float4v tanh4(float4v a) {
  float4v r;
#pragma unroll
  for (int i = 0; i < 4; ++i) r[i] = tanh_pre(a[i]);
  return r;
}

// Light barrier: LDS-visibility only (no vmcnt drain -> ring stores /
// prefetch loads stay in flight across steps). Rule #18: sched_barrier
// fences around the asm so nothing is hoisted past the waitcnt.
__device__ __forceinline__ void bar_light() {
  __builtin_amdgcn_sched_barrier(0);
  asm volatile("s_waitcnt lgkmcnt(0)" ::: "memory");
  __builtin_amdgcn_s_barrier();
  asm volatile("" ::: "memory");
  __builtin_amdgcn_sched_barrier(0);
}
// Full barrier: also drains vmcnt in EVERY wave (required before the
// producer's flag release: all waves' ring stores must be complete).
__device__ __forceinline__ void bar_full() {
  __builtin_amdgcn_sched_barrier(0);
  asm volatile("s_waitcnt vmcnt(0) lgkmcnt(0)" ::: "memory");
  __builtin_amdgcn_s_barrier();
  asm volatile("" ::: "memory");
  __builtin_amdgcn_sched_barrier(0);
}

__device__ __forceinline__ half8 make_afrag(const float* __restrict__ W, int K, int row, int col, float sc) {
  const float* p = W + (size_t)row * K + col;
  float4 a = *(const float4*)p;
  float4 b = *(const float4*)(p + 4);
  half8 h;
  h[0]=(_Float16)(a.x*sc); h[1]=(_Float16)(a.y*sc); h[2]=(_Float16)(a.z*sc); h[3]=(_Float16)(a.w*sc);
  h[4]=(_Float16)(b.x*sc); h[5]=(_Float16)(b.y*sc); h[6]=(_Float16)(b.z*sc); h[7]=(_Float16)(b.w*sc);
  return h;
}

__device__ __forceinline__ void wait_ge(int* p, int want) {
  while (__hip_atomic_load(p, __ATOMIC_RELAXED, __HIP_MEMORY_SCOPE_AGENT) < want)
    __builtin_amdgcn_s_sleep(2);
}

__global__ void ring_init(int* f) { if (threadIdx.x < 16) f[threadIdx.x] = 0; }

__global__ __launch_bounds__(512) void lstm_wavefront(
    const float* __restrict__ x, const float* __restrict__ w_ih0,
    const float* __restrict__ w_hh0, const float* __restrict__ w_ih1,
    const float* __restrict__ w_hh1, const float* __restrict__ fc_w,
    const float* __restrict__ fc_b, float* __restrict__ out, char* __restrict__ ws)
{
  const int tid  = threadIdx.x, lane = tid & 63, w = tid >> 6;
  const int quad = lane >> 4, n = lane & 15;
  const int g = blockIdx.x & 7, layer = blockIdx.x >> 3;  // L0/L1 pair per XCD
  _Float16* ring = (_Float16*)ws + (size_t)g * GRP_ELEMS;
  int* flag     = (int*)(ws + RING_BYTES) + g;        // chunks produced by L0
  int* consumed = (int*)(ws + RING_BYTES) + 8 + g;    // chunks consumed by L1

  __shared__ char sh_x[4 * 16 * XSTR];   // 4-deep: x staged 2 steps ahead
  __shared__ char sh_h[2 * 16 * HSTR];   // double-buffered h

  const size_t hn_base = (size_t)T_ * B_ * OUT_;
  float4v c = {0.f, 0.f, 0.f, 0.f};
  float hf[4] = {0.f, 0.f, 0.f, 0.f};

  for (int i = tid; i < 2 * 16 * HSTR / 4; i += 512) ((unsigned*)sh_h)[i] = 0u;

  if (layer == 0) {
    // ================= LAYER 0 (producer) =================
    half8 a_x[4][2], a_h[4][4];
#pragma unroll
    for (int gt = 0; gt < 4; ++gt) {
      const float sc = (gt == 2) ? C2LOG2E : NLOG2E;
      const int row = gt * H_ + w * 16 + n;
#pragma unroll
      for (int kt = 0; kt < 2; ++kt) a_x[gt][kt] = make_afrag(w_ih0, IN_, row, kt * 32 + quad * 8, sc);
#pragma unroll
      for (int kt = 0; kt < 4; ++kt) a_h[gt][kt] = make_afrag(w_hh0, H_, row, kt * 32 + quad * 8, sc);
    }
    const int xn = tid >> 5, xk = (tid & 31) * 2;
#pragma unroll
    for (int k = 0; k < 2; ++k) {   // stage x(0), x(1)
      float2 xv = *(const float2*)(x + ((size_t)k * B_ + g * 16 + xn) * IN_ + xk);
      _Float16* d = (_Float16*)(sh_x + k * 16 * XSTR + xn * XSTR + xk * 2);
      d[0] = (_Float16)xv.x; d[1] = (_Float16)xv.y;
    }
    __syncthreads();
    half4v hh_def = {0, 0, 0, 0};

#pragma unroll 2
    for (int t = 0; t < T_; ++t) {
      const int ck = t >> 5, s = t & (CH_ - 1);
      if (s == 0 && ck >= RING_) wait_ge(consumed, ck - 1);  // all threads poll
      // deferred ring store of y0(t-1): stays in flight (no per-step drain)
      if (t > 0)
        *(half4v*)(ring + ((size_t)((t - 1) & 63) * 16 + n) * 128 + w * 16 + quad * 4) = hh_def;
      float2 xv = make_float2(0.f, 0.f);
      if (t + 2 < T_) xv = *(const float2*)(x + ((size_t)(t + 2) * B_ + g * 16 + xn) * IN_ + xk);

      half8 Bx[2], Bh[4];
#pragma unroll
      for (int kt = 0; kt < 2; ++kt)
        Bx[kt] = *(const half8*)(sh_x + (t & 3) * 16 * XSTR + n * XSTR + (kt * 32 + quad * 8) * 2);
#pragma unroll
      for (int kt = 0; kt < 4; ++kt)
        Bh[kt] = *(const half8*)(sh_h + (t & 1) * 16 * HSTR + n * HSTR + (kt * 32 + quad * 8) * 2);

      // kt-major interleave: adjacent MFMAs belong to different gates ->
      // dep distance 4, MFMA latency hidden
      float4v acc[4];
#pragma unroll
      for (int gt = 0; gt < 4; ++gt) acc[gt] = (float4v){0.f, 0.f, 0.f, 0.f};
#pragma unroll
      for (int kt = 0; kt < 2; ++kt)
#pragma unroll
        for (int gt = 0; gt < 4; ++gt)
          acc[gt] = __builtin_amdgcn_mfma_f32_16x16x32_f16(a_x[gt][kt], Bx[kt], acc[gt], 0, 0, 0);
#pragma unroll
      for (int kt = 0; kt < 4; ++kt)
#pragma unroll
        for (int gt = 0; gt < 4; ++gt)
          acc[gt] = __builtin_amdgcn_mfma_f32_16x16x32_f16(a_h[gt][kt], Bh[kt], acc[gt], 0, 0, 0);
      float4v ga[4];
#pragma unroll
      for (int gt = 0; gt < 4; ++gt) ga[gt] = (gt == 2) ? tanh4(acc[gt]) : sigm4(acc[gt]);

      half4v hh;
#pragma unroll
      for (int r = 0; r < 4; ++r) {
        c[r] = fmaf(ga[1][r], c[r], ga[0][r] * ga[2][r]);
        hf[r] = ga[3][r] * tanh_c(c[r]);
        hh[r] = (_Float16)hf[r];
      }
      *(half4v*)(sh_h + ((t & 1) ^ 1) * 16 * HSTR + n * HSTR + (w * 16 + quad * 4) * 2) = hh;
      hh_def = hh;
      if (t + 2 < T_) {
        _Float16* d = (_Float16*)(sh_x + ((t + 2) & 3) * 16 * XSTR + xn * XSTR + xk * 2);
        d[0] = (_Float16)xv.x; d[1] = (_Float16)xv.y;
      }
      // full drain only at chunk boundary (flag release needs ALL waves'
      // ring stores complete); light barrier otherwise
      if (s == 0) bar_full(); else bar_light();
      if (tid == 0 && s == 0 && t > 0) {     // chunks 0..ck-1 fully stored+drained
        __builtin_amdgcn_fence(__ATOMIC_RELEASE, "agent");
        __hip_atomic_store(flag, ck, __ATOMIC_RELAXED, __HIP_MEMORY_SCOPE_AGENT);
      }
    }
    // epilogue: final y0(T-1) + flag T_/CH_
    *(half4v*)(ring + ((size_t)((T_ - 1) & 63) * 16 + n) * 128 + w * 16 + quad * 4) = hh_def;
    bar_full();
    if (tid == 0) {
      __builtin_amdgcn_fence(__ATOMIC_RELEASE, "agent");
      __hip_atomic_store(flag, T_ / CH_, __ATOMIC_RELAXED, __HIP_MEMORY_SCOPE_AGENT);
    }
    {
      float* hn = out + hn_base;
      float* cn = out + hn_base + 2 * (size_t)B_ * H_;
      size_t idx = (size_t)(g * 16 + n) * H_ + w * 16 + quad * 4;
      *(float4*)(hn + idx) = make_float4(hf[0], hf[1], hf[2], hf[3]);
      *(float4*)(cn + idx) = make_float4(c[0], c[1], c[2], c[3]);
    }
  } else {
    // ================= LAYER 1 + FC (consumer) =================
    half8 a_i[4][4], a_h[4][4], a_fc[4];
#pragma unroll
    for (int gt = 0; gt < 4; ++gt) {
      const float sc = (gt == 2) ? C2LOG2E : NLOG2E;
      const int row = gt * H_ + w * 16 + n;
#pragma unroll
      for (int kt = 0; kt < 4; ++kt) {
        a_i[gt][kt] = make_afrag(w_ih1, H_, row, kt * 32 + quad * 8, sc);
        a_h[gt][kt] = make_afrag(w_hh1, H_, row, kt * 32 + quad * 8, sc);
      }
    }
    float4 fb = make_float4(0.f, 0.f, 0.f, 0.f);
    if (w < 2) {
#pragma unroll
      for (int kt = 0; kt < 4; ++kt) a_fc[kt] = make_afrag(fc_w, H_, w * 16 + n, kt * 32 + quad * 8, 1.0f);
      fb = *(const float4*)(fc_b + w * 16 + quad * 4);
    }
    __syncthreads();
    half8 By[4];

#pragma unroll 2
    for (int t = 0; t < T_; ++t) {
      const int ck = t >> 5, s = t & (CH_ - 1);
      if (s == 0) {                          // chunk boundary: serial load
        wait_ge(flag, ck + 1);
        __builtin_amdgcn_fence(__ATOMIC_ACQUIRE, "agent");
        const _Float16* yp = ring + ((size_t)(t & 63) * 16 + n) * 128 + quad * 8;
#pragma unroll
        for (int kt = 0; kt < 4; ++kt) By[kt] = *(const half8*)(yp + kt * 32);
      }
      // h1(t-1) fragments from LDS; FC(t-1) reuses them
      half8 Bh[4];
#pragma unroll
      for (int kt = 0; kt < 4; ++kt)
        Bh[kt] = *(const half8*)(sh_h + (t & 1) * 16 * HSTR + n * HSTR + (kt * 32 + quad * 8) * 2);
      if (w < 2 && t > 0) {
        // FC as two 2-deep chains (was one 4-deep chain)
        float4v af0 = {0.f, 0.f, 0.f, 0.f}, af1 = {0.f, 0.f, 0.f, 0.f};
        af0 = __builtin_amdgcn_mfma_f32_16x16x32_f16(a_fc[0], Bh[0], af0, 0, 0, 0);
        af1 = __builtin_amdgcn_mfma_f32_16x16x32_f16(a_fc[1], Bh[1], af1, 0, 0, 0);
        af0 = __builtin_amdgcn_mfma_f32_16x16x32_f16(a_fc[2], Bh[2], af0, 0, 0, 0);
        af1 = __builtin_amdgcn_mfma_f32_16x16x32_f16(a_fc[3], Bh[3], af1, 0, 0, 0);
        float* op = out + ((size_t)(t - 1) * B_ + g * 16 + n) * OUT_ + w * 16 + quad * 4;
        *(float4*)op = make_float4(af0[0] + af1[0] + fb.x, af0[1] + af1[1] + fb.y,
                                   af0[2] + af1[2] + fb.z, af0[3] + af1[3] + fb.w);
      }
      // kt-major interleave (see L0): dep distance 4 instead of 8-deep chains
      float4v acc[4];
#pragma unroll
      for (int gt = 0; gt < 4; ++gt) acc[gt] = (float4v){0.f, 0.f, 0.f, 0.f};
#pragma unroll
      for (int kt = 0; kt < 4; ++kt)
#pragma unroll
        for (int gt = 0; gt < 4; ++gt)
          acc[gt] = __builtin_amdgcn_mfma_f32_16x16x32_f16(a_i[gt][kt], By[kt], acc[gt], 0, 0, 0);
#pragma unroll
      for (int kt = 0; kt < 4; ++kt)
#pragma unroll
        for (int gt = 0; gt < 4; ++gt)
          acc[gt] = __builtin_amdgcn_mfma_f32_16x16x32_f16(a_h[gt][kt], Bh[kt], acc[gt], 0, 0, 0);
      float4v ga[4];
#pragma unroll
      for (int gt = 0; gt < 4; ++gt) ga[gt] = (gt == 2) ? tanh4(acc[gt]) : sigm4(acc[gt]);

      // prefetch By(t+1): issued here, consumed NEXT step; light barrier
      // keeps it in flight across the step boundary (latency fully hidden)
      half8 Byn[4];
      const bool pf = (s != CH_ - 1) && (t + 1 < T_);
      if (pf) {
        const _Float16* yp = ring + ((size_t)((t + 1) & 63) * 16 + n) * 128 + quad * 8;
#pragma unroll
        for (int kt = 0; kt < 4; ++kt) Byn[kt] = *(const half8*)(yp + kt * 32);
      }
      half4v hh;
#pragma unroll
      for (int r = 0; r < 4; ++r) {
        c[r] = fmaf(ga[1][r], c[r], ga[0][r] * ga[2][r]);
        hf[r] = ga[3][r] * tanh_c(c[r]);
        hh[r] = (_Float16)hf[r];
      }
      *(half4v*)(sh_h + ((t & 1) ^ 1) * 16 * HSTR + n * HSTR + (w * 16 + quad * 4) * 2) = hh;
      bar_light();   // consumed-release needs only register-consumed reads
      if (s == CH_ - 1 && tid == 0) {
        __builtin_amdgcn_fence(__ATOMIC_RELEASE, "agent");
        __hip_atomic_store(consumed, ck + 1, __ATOMIC_RELAXED, __HIP_MEMORY_SCOPE_AGENT);
      }
      if (pf) {
#pragma unroll
        for (int kt = 0; kt < 4; ++kt) By[kt] = Byn[kt];
      }
    }
    // FC(T-1) from sh_h slot (T_&1)=0 = h1(T-1)
    if (w < 2) {
      float4v af = {0.f, 0.f, 0.f, 0.f};
#pragma unroll
      for (int kt = 0; kt < 4; ++kt) {
        half8 Bh = *(const half8*)(sh_h + (T_ & 1) * 16 * HSTR + n * HSTR + (kt * 32 + quad * 8) * 2);
        af = __builtin_amdgcn_mfma_f32_16x16x32_f16(a_fc[kt], Bh, af, 0, 0, 0);
      }
      float* op = out + ((size_t)(T_ - 1) * B_ + g * 16 + n) * OUT_ + w * 16 + quad * 4;
      *(float4*)op = make_float4(af[0] + fb.x, af[1] + fb.y, af[2] + fb.z, af[3] + fb.w);
    }
    {
      float* hn = out + hn_base + (size_t)B_ * H_;
      float* cn = out + hn_base + 3 * (size_t)B_ * H_;
      size_t idx = (size_t)(g * 16 + n) * H_ + w * 16 + quad * 4;
      *(float4*)(hn + idx) = make_float4(hf[0], hf[1], hf[2], hf[3]);
      *(float4*)(cn + idx) = make_float4(c[0], c[1], c[2], c[3]);
    }
  }
}

extern "C" void kernel_launch(void* const* d_in, const int* in_sizes, int n_in,
                              void* d_out, int out_size, void* d_ws, size_t ws_size,
                              hipStream_t stream) {
  const float* x     = (const float*)d_in[0];
  const float* w_ih0 = (const float*)d_in[1];
  const float* w_hh0 = (const float*)d_in[2];
  const float* w_ih1 = (const float*)d_in[3];
  const float* w_hh1 = (const float*)d_in[4];
  const float* fc_w  = (const float*)d_in[5];
  const float* fc_b  = (const float*)d_in[6];
  char* ws = (char*)d_ws;
  ring_init<<<1, 64, 0, stream>>>((int*)(ws + RING_BYTES));
  lstm_wavefront<<<16, 512, 0, stream>>>(x, w_ih0, w_hh0, w_ih1, w_hh1,
                                         fc_w, fc_b, (float*)d_out, ws);
}